// Round 2
// baseline (168934.229 us; speedup 1.0000x reference)
//
#include <hip/hip_runtime.h>
#include <cmath>

// Problem constants
#define B 32
#define T 512
#define D_IN 512
#define H 1024
#define NG 4096       // 4*H
#define L 4
#define D_OUT 512
#define RING 8        // h ring-buffer depth (power of 2)
#define CK 128        // K-chunk staged in LDS
#define APAD 36       // padded LDS row (words): 36*4=144B, 16B-aligned rows, bank-rotated

// ring slot for timestep t (t >= -1); t=-1 -> slot 0 (zeroed)
__device__ __forceinline__ int slot(int t) { return (t + 1) & (RING - 1); }

__device__ __forceinline__ float sigf(float x) { return 1.f / (1.f + __expf(-x)); }
__device__ __forceinline__ float tanhfast(float x) { return 2.f / (1.f + __expf(-2.f * x)) - 1.f; }

// ---------------------------------------------------------------------------
// Persistent wavefront LSTM.
// Grid = 256 blocks x 256 threads, all co-resident (<= 1 block/CU capacity).
// Block = (layer l = blockIdx>>6, wg = blockIdx&63). wg owns hidden units
// [wg*16, wg*16+16) of its layer: computes all 4 gates for those units over
// all 32 batch rows, does the cell update locally; c-state stays in VGPRs for
// all 512 steps. h is published through a ring in d_ws with device-scope
// flags (wavefront pipelining across layers).
// Thread layout: wave w (0..3); rg=lane>>5; rows row0=8w+4rg..+3 (4 rows);
// c=lane&31 -> gate cols {c, c+32} of the wg's 64-col slice (col j: gate=j>>4,
// unit=j&15). Per k: 1 ds_read_b128 (4 rows' activations, broadcast) +
// 2 weight loads (L1-hit across waves) + 8 FMA -> VALU-bound.
// ---------------------------------------------------------------------------
__global__ __launch_bounds__(256) void lstm_persistent(
    const float* __restrict__ x,     // [B,T,D_IN]
    const float* __restrict__ Wx0,   // [D_IN,4H]
    const float* __restrict__ Wh0,   // [H,4H]
    const float* __restrict__ b0,    // [4H]
    const float* __restrict__ Wx,    // [L-1,H,4H]
    const float* __restrict__ Wh,    // [L-1,H,4H]
    const float* __restrict__ bb,    // [L-1,4H]
    const float* __restrict__ Wout,  // [H,D_OUT]
    const float* __restrict__ bout,  // [D_OUT]
    float* __restrict__ out,         // [B,D_OUT]
    float* __restrict__ ring,        // [L][RING][B*H]
    int*   __restrict__ flags)       // [L][T]
{
    __shared__ float a_sh[CK * APAD];   // 18 KiB

    const int tid  = threadIdx.x;
    const int l    = blockIdx.x >> 6;
    const int wg   = blockIdx.x & 63;

    const int lane = tid & 63;
    const int w    = tid >> 6;
    const int rg   = lane >> 5;
    const int row0 = w * 8 + rg * 4;     // rows row0..row0+3
    const int c    = lane & 31;
    const int u    = c & 15;
    const int gsel = c >> 4;             // 0: holds gates (i,g); 1: holds (f,o)
    const int off0 = (gsel << 10) + (wg << 4) + u;   // col of gate gsel
    const int off1 = off0 + 2048;                     // col of gate gsel+2

    const float* Wxl; const float* Whl; const float* biasl; int Kin;
    if (l == 0) { Wxl = Wx0; Whl = Wh0; biasl = b0; Kin = D_IN; }
    else {
        Wxl   = Wx + (size_t)(l - 1) * H * NG;
        Whl   = Wh + (size_t)(l - 1) * H * NG;
        biasl = bb + (size_t)(l - 1) * NG;
        Kin   = H;
    }
    const float bj0 = biasl[off0];
    const float bj1 = biasl[off1];

    float* ringl        = ring + (size_t)l * RING * (B * H);
    const float* ringin = (l > 0) ? (ring + (size_t)(l - 1) * RING * (B * H)) : nullptr;

    float c4[4] = {0.f, 0.f, 0.f, 0.f};   // cell state, resident in VGPRs

    const int nchx = Kin / CK;   // 4 (layer 0) or 8
    const int nchh = H / CK;     // 8

    for (int t = 0; t < T; ++t) {
        // ---- waits: input ready, own recurrence ready, ring back-pressure ----
        if (tid == 0) {
            if (l > 0)
                while (__hip_atomic_load(&flags[(l - 1) * T + t], __ATOMIC_ACQUIRE,
                                         __HIP_MEMORY_SCOPE_AGENT) < 64)
                    __builtin_amdgcn_s_sleep(2);
            if (t > 0)
                while (__hip_atomic_load(&flags[l * T + (t - 1)], __ATOMIC_ACQUIRE,
                                         __HIP_MEMORY_SCOPE_AGENT) < 64)
                    __builtin_amdgcn_s_sleep(2);
            if (l < L - 1 && t >= RING)
                while (__hip_atomic_load(&flags[(l + 1) * T + (t - RING)], __ATOMIC_ACQUIRE,
                                         __HIP_MEMORY_SCOPE_AGENT) < 64)
                    __builtin_amdgcn_s_sleep(2);
        }
        __syncthreads();

        float acc[2][4] = {{0.f,0.f,0.f,0.f},{0.f,0.f,0.f,0.f}};

        // ---- x-part: input from x (l=0) or h_{l-1}(t) ----
        for (int ch = 0; ch < nchx; ++ch) {
            const int k0 = ch * CK;
            for (int i = tid; i < B * CK; i += 256) {
                const int b  = i >> 7;          // CK==128
                const int kk = i & (CK - 1);
                float v;
                if (l == 0)
                    v = x[(size_t)b * (T * D_IN) + (size_t)t * D_IN + k0 + kk];
                else
                    v = __hip_atomic_load(&ringin[(size_t)slot(t) * (B * H) + (size_t)b * H + k0 + kk],
                                          __ATOMIC_RELAXED, __HIP_MEMORY_SCOPE_AGENT);
                a_sh[kk * APAD + b] = v;        // transposed: [kk][b]
            }
            __syncthreads();
            const float* wr = Wxl + (size_t)k0 * NG;
            #pragma unroll 4
            for (int kk = 0; kk < CK; ++kk) {
                float4 a4 = *(const float4*)&a_sh[kk * APAD + row0];
                float w0 = wr[off0];
                float w1 = wr[off1];
                wr += NG;
                acc[0][0] += a4.x * w0; acc[0][1] += a4.y * w0;
                acc[0][2] += a4.z * w0; acc[0][3] += a4.w * w0;
                acc[1][0] += a4.x * w1; acc[1][1] += a4.y * w1;
                acc[1][2] += a4.z * w1; acc[1][3] += a4.w * w1;
            }
            __syncthreads();
        }

        // ---- h-part: own layer's h(t-1) ----
        for (int ch = 0; ch < nchh; ++ch) {
            const int k0 = ch * CK;
            for (int i = tid; i < B * CK; i += 256) {
                const int b  = i >> 7;
                const int kk = i & (CK - 1);
                float v = __hip_atomic_load(&ringl[(size_t)slot(t - 1) * (B * H) + (size_t)b * H + k0 + kk],
                                            __ATOMIC_RELAXED, __HIP_MEMORY_SCOPE_AGENT);
                a_sh[kk * APAD + b] = v;
            }
            __syncthreads();
            const float* wr = Whl + (size_t)k0 * NG;
            #pragma unroll 4
            for (int kk = 0; kk < CK; ++kk) {
                float4 a4 = *(const float4*)&a_sh[kk * APAD + row0];
                float w0 = wr[off0];
                float w1 = wr[off1];
                wr += NG;
                acc[0][0] += a4.x * w0; acc[0][1] += a4.y * w0;
                acc[0][2] += a4.z * w0; acc[0][3] += a4.w * w0;
                acc[1][0] += a4.x * w1; acc[1][1] += a4.y * w1;
                acc[1][2] += a4.z * w1; acc[1][3] += a4.w * w1;
            }
            __syncthreads();
        }

        // ---- cell update: pair lanes (c, c^16) to assemble (i,f,g,o) ----
        float* hdst = ringl + (size_t)slot(t) * (B * H);
        #pragma unroll
        for (int r = 0; r < 4; ++r) {
            float g0 = acc[0][r] + bj0;   // gsel==0: i ; gsel==1: f
            float g1 = acc[1][r] + bj1;   // gsel==0: g ; gsel==1: o
            float p0 = __shfl_xor(g0, 16, 64);
            float p1 = __shfl_xor(g1, 16, 64);
            float vi = gsel ? p0 : g0;
            float vf = gsel ? g0 : p0;
            float vg = gsel ? p1 : g1;
            float vo = gsel ? g1 : p1;
            float cn = sigf(vf) * c4[r] + sigf(vi) * tanhfast(vg);
            c4[r] = cn;
            float hv = sigf(vo) * tanhfast(cn);
            if (gsel == 0)
                __hip_atomic_store(&hdst[(size_t)(row0 + r) * H + (wg << 4) + u], hv,
                                   __ATOMIC_RELAXED, __HIP_MEMORY_SCOPE_AGENT);
        }
        __threadfence();       // agent-scope: make h visible before flag
        __syncthreads();
        if (tid == 0)
            __hip_atomic_fetch_add(&flags[l * T + t], 1, __ATOMIC_RELEASE,
                                   __HIP_MEMORY_SCOPE_AGENT);
    }

    // ---- output projection: out = h3(T-1) @ Wout + bout ----
    if (tid == 0)
        while (__hip_atomic_load(&flags[(L - 1) * T + (T - 1)], __ATOMIC_ACQUIRE,
                                 __HIP_MEMORY_SCOPE_AGENT) < 64)
            __builtin_amdgcn_s_sleep(2);
    __syncthreads();

    if (blockIdx.x < 64) {
        const int b  = blockIdx.x >> 1;
        const int o0 = (blockIdx.x & 1) << 8;
        const float* h3 = ring + (size_t)(L - 1) * RING * (B * H)
                               + (size_t)slot(T - 1) * (B * H) + (size_t)b * H;
        for (int j = tid; j < H; j += 256)
            a_sh[j] = __hip_atomic_load(&h3[j], __ATOMIC_RELAXED, __HIP_MEMORY_SCOPE_AGENT);
        __syncthreads();
        const int o = o0 + tid;
        float s = bout[o];
        #pragma unroll 8
        for (int j = 0; j < H; ++j)
            s += a_sh[j] * Wout[(size_t)j * D_OUT + o];
        out[(size_t)b * D_OUT + o] = s;
    }
}

extern "C" void kernel_launch(void* const* d_in, const int* in_sizes, int n_in,
                              void* d_out, int out_size, void* d_ws, size_t ws_size,
                              hipStream_t stream) {
    const float* x    = (const float*)d_in[0];
    const float* Wx0  = (const float*)d_in[1];
    const float* Wh0  = (const float*)d_in[2];
    const float* b0   = (const float*)d_in[3];
    const float* Wx   = (const float*)d_in[4];
    const float* Wh   = (const float*)d_in[5];
    const float* bb   = (const float*)d_in[6];
    const float* Wout = (const float*)d_in[7];
    const float* bout = (const float*)d_in[8];
    float* out = (float*)d_out;

    // Workspace: ring [L][RING][B*H] floats + flags [L][T] ints  (~4.2 MB)
    float* ring  = (float*)d_ws;
    size_t ring_floats = (size_t)L * RING * B * H;
    int*   flags = (int*)(ring + ring_floats);
    size_t total_bytes = ring_floats * sizeof(float) + (size_t)L * T * sizeof(int);

    hipMemsetAsync(d_ws, 0, total_bytes, stream);

    lstm_persistent<<<dim3(256), dim3(256), 0, stream>>>(
        x, Wx0, Wh0, b0, Wx, Wh, bb, Wout, bout, out, ring, flags);
}

// Round 3
// 108359.827 us; speedup vs baseline: 1.5590x; 1.5590x over previous
//
#include <hip/hip_runtime.h>
#include <hip/hip_fp16.h>
#include <cmath>

// Problem constants
#define B 32
#define T 512
#define D_IN 512
#define H 1024
#define NG 4096
#define L 4
#define D_OUT 512
#define RING 8
#define CK 128          // k-chunk staged in LDS
#define AS 36           // a_sh row stride (words): 144B rows -> b128 reads 16B-aligned

// ws layout (u32 units):
//   Wxpk [l][wg][kq][w'][ki]  : l0: 64*512*32 = 1,048,576 ; l>=1: 3*64*1024*32 = 6,291,456
//   Whpk [l][wg][k][w']       : 4*64*1024*32 = 8,388,608   (base +7,340,032)
//   ring  [L][RING][B*H] f32  : 1,048,576 floats           (base +15,728,640 u32)
//   flags [L][T] int
#define XTOT 7340032u
#define HTOT 8388608u
#define WTOT 15728640u

__device__ __forceinline__ int slot(int t) { return (t + 1) & (RING - 1); }
__device__ __forceinline__ float sigf(float x) { return 1.f / (1.f + __expf(-x)); }
__device__ __forceinline__ float tanhfast(float x) { return 2.f / (1.f + __expf(-2.f * x)) - 1.f; }

// ---------------------------------------------------------------------------
// Pack kernels: fp32 weights -> packed fp16 gate-pairs.
// u32 = ( fp16(W[k][colA]) , fp16(W[k][colA+2048]) ), colA = gsel*1024+wg*16+u
// ---------------------------------------------------------------------------
__global__ __launch_bounds__(256) void pack_h(const float* __restrict__ Wh0,
                                              const float* __restrict__ Wh,
                                              uint32_t* __restrict__ dst) {
    unsigned i = blockIdx.x * 256 + threadIdx.x;          // < 8,388,608
    int wp = i & 31, k = (i >> 5) & 1023, wg = (i >> 15) & 63, l = i >> 21;
    int u = wp & 15, gsel = wp >> 4;
    int colA = gsel * 1024 + wg * 16 + u;
    const float* src = (l == 0) ? Wh0 : (Wh + (size_t)(l - 1) * H * NG);
    float a = src[(size_t)k * NG + colA];
    float b = src[(size_t)k * NG + colA + 2048];
    __half2 h2 = __halves2half2(__float2half_rn(a), __float2half_rn(b));
    union { __half2 h; uint32_t u; } cv; cv.h = h2;
    dst[i] = cv.u;
}

__global__ __launch_bounds__(256) void pack_x(const float* __restrict__ Wx0,
                                              const float* __restrict__ Wx,
                                              uint32_t* __restrict__ dst) {
    unsigned i = blockIdx.x * 256 + threadIdx.x;          // < 7,340,032
    int l, wg; unsigned r;
    if (i < 1048576u) { l = 0; r = i & 16383u; wg = i >> 14; }
    else { unsigned j = i - 1048576u; l = 1 + (j >> 21); r = j & 2097151u; wg = (r >> 15); r &= 32767u; }
    int kq = r >> 7, wp = (r >> 2) & 31, ki = r & 3;
    int k = kq * 4 + ki;
    int u = wp & 15, gsel = wp >> 4;
    int colA = gsel * 1024 + wg * 16 + u;
    const float* src = (l == 0) ? Wx0 : (Wx + (size_t)(l - 1) * H * NG);
    float a = src[(size_t)k * NG + colA];
    float b = src[(size_t)k * NG + colA + 2048];
    __half2 h2 = __halves2half2(__float2half_rn(a), __float2half_rn(b));
    union { __half2 h; uint32_t u; } cv; cv.h = h2;
    dst[i] = cv.u;
}

// ---------------------------------------------------------------------------
// Persistent pipelined LSTM. 256 blocks = 4 layers x 64 wg, all co-resident.
// Wh-slice (131 KB fp16) resident in LDS for all 512 steps; Wx-slice streamed
// (L2-resident, coalesced dwordx4). Activations fp32. c-state in VGPRs.
// ---------------------------------------------------------------------------
__global__ __launch_bounds__(256, 1) void lstm_persistent(
    const float* __restrict__ x,
    const float* __restrict__ b0,
    const float* __restrict__ bb,
    const float* __restrict__ Wout,
    const float* __restrict__ bout,
    float* __restrict__ out,
    const uint32_t* __restrict__ Wpk,
    float* __restrict__ ring,
    int*   __restrict__ flags)
{
    extern __shared__ char smem[];
    uint32_t* w_sh = (uint32_t*)smem;                 // [1024][32] u32 = 131072 B
    float*    a_sh = (float*)(smem + 131072);         // [CK][AS]         18432 B

    const int tid  = threadIdx.x;
    const int l    = blockIdx.x >> 6;
    const int wg   = blockIdx.x & 63;

    const int lane = tid & 63;
    const int w    = tid >> 6;
    const int rg   = lane >> 5;
    const int row0 = w * 8 + rg * 4;
    const int c    = lane & 31;
    const int u    = c & 15;
    const int gsel = c >> 4;
    const int colA = gsel * 1024 + (wg << 4) + u;     // acc0 col; acc1 = colA+2048

    const float* biasl = (l == 0) ? b0 : (bb + (size_t)(l - 1) * NG);
    const float bj0 = biasl[colA];
    const float bj1 = biasl[colA + 2048];
    const int Kin = (l == 0) ? D_IN : H;
    const int nx  = Kin / CK;

    // Wx stream base (uint4 view: [Kin/4][32])
    size_t xbase = (l == 0) ? ((size_t)wg << 14)
                            : (1048576ULL + (((size_t)(l - 1) * 64 + wg) << 15));
    const uint4* wx4 = (const uint4*)(Wpk + xbase);

    // ---- load Wh slice into LDS (one-time) ----
    {
        const uint4* whb = (const uint4*)(Wpk + XTOT + (((size_t)l * 64 + wg) << 15));
        uint4* wsh4 = (uint4*)w_sh;
        for (int q = tid; q < 8192; q += 256) wsh4[q] = whb[q];
    }

    float* ringl        = ring + (size_t)l * RING * (B * H);
    float* ringin       = (l > 0) ? (ring + (size_t)(l - 1) * RING * (B * H)) : nullptr;

    float c4[4] = {0.f, 0.f, 0.f, 0.f};
    float acc0[4], acc1[4];
    __syncthreads();

    for (int t = 0; t < T; ++t) {
        // wait own layer's h(t-1) complete
        if (t > 0) {
            if (tid == 0)
                while (__hip_atomic_load(&flags[l * T + (t - 1)], __ATOMIC_ACQUIRE,
                                         __HIP_MEMORY_SCOPE_AGENT) < 64)
                    __builtin_amdgcn_s_sleep(1);
            __syncthreads();
        }

        #pragma unroll
        for (int r = 0; r < 4; ++r) { acc0[r] = 0.f; acc1[r] = 0.f; }

        // ================= h-phase: h(t-1) @ Wh (LDS weights) =================
        float* hsrc = ringl + (size_t)slot(t - 1) * (B * H);
        for (int ch = 0; ch < 8; ++ch) {
            const int k0 = ch * CK;
            for (int i = tid; i < B * CK; i += 256) {
                int b  = i >> 7;
                int kk = i & (CK - 1);
                float v = __hip_atomic_load(&hsrc[(size_t)b * H + k0 + kk],
                                            __ATOMIC_RELAXED, __HIP_MEMORY_SCOPE_AGENT);
                a_sh[kk * AS + b] = v;
            }
            __syncthreads();
            const uint32_t* wrow = w_sh + k0 * 32 + c;
            #pragma unroll 4
            for (int kk = 0; kk < CK; ++kk) {
                uint32_t wv = wrow[kk * 32];
                union { uint32_t u; __half2 h; } cv; cv.u = wv;
                float2 wf = __half22float2(cv.h);
                const float4 a4 = *(const float4*)&a_sh[kk * AS + row0];
                acc0[0] += a4.x * wf.x; acc0[1] += a4.y * wf.x;
                acc0[2] += a4.z * wf.x; acc0[3] += a4.w * wf.x;
                acc1[0] += a4.x * wf.y; acc1[1] += a4.y * wf.y;
                acc1[2] += a4.z * wf.y; acc1[3] += a4.w * wf.y;
            }
            __syncthreads();
        }

        // wait upstream h(t) ready; downstream consumed slot(t-RING)
        if (tid == 0) {
            if (l > 0)
                while (__hip_atomic_load(&flags[(l - 1) * T + t], __ATOMIC_ACQUIRE,
                                         __HIP_MEMORY_SCOPE_AGENT) < 64)
                    __builtin_amdgcn_s_sleep(1);
            if (l < L - 1 && t >= RING)
                while (__hip_atomic_load(&flags[(l + 1) * T + (t - RING)], __ATOMIC_ACQUIRE,
                                         __HIP_MEMORY_SCOPE_AGENT) < 64)
                    __builtin_amdgcn_s_sleep(1);
        }
        __syncthreads();

        // ================= x-phase: input @ Wx (streamed weights) =============
        for (int ch = 0; ch < nx; ++ch) {
            const int k0 = ch * CK;
            if (l == 0) {
                for (int q = tid; q < B * CK / 4; q += 256) {     // 1024 float4s
                    int b = q >> 5, kq4 = q & 31;
                    float4 v = *(const float4*)&x[(size_t)b * (T * D_IN) + (size_t)t * D_IN + k0 + kq4 * 4];
                    a_sh[(kq4 * 4 + 0) * AS + b] = v.x;
                    a_sh[(kq4 * 4 + 1) * AS + b] = v.y;
                    a_sh[(kq4 * 4 + 2) * AS + b] = v.z;
                    a_sh[(kq4 * 4 + 3) * AS + b] = v.w;
                }
            } else {
                float* xsrc = ringin + (size_t)slot(t) * (B * H);
                for (int i = tid; i < B * CK; i += 256) {
                    int b  = i >> 7;
                    int kk = i & (CK - 1);
                    float v = __hip_atomic_load(&xsrc[(size_t)b * H + k0 + kk],
                                                __ATOMIC_RELAXED, __HIP_MEMORY_SCOPE_AGENT);
                    a_sh[kk * AS + b] = v;
                }
            }
            __syncthreads();
            const uint4* wxc = wx4 + (size_t)(ch * 32) * 32 + c;
            #pragma unroll 4
            for (int kq = 0; kq < 32; ++kq) {
                uint4 wv = wxc[(size_t)kq * 32];
                const uint32_t wvs[4] = {wv.x, wv.y, wv.z, wv.w};
                #pragma unroll
                for (int ki = 0; ki < 4; ++ki) {
                    union { uint32_t u; __half2 h; } cv; cv.u = wvs[ki];
                    float2 wf = __half22float2(cv.h);
                    const float4 a4 = *(const float4*)&a_sh[(kq * 4 + ki) * AS + row0];
                    acc0[0] += a4.x * wf.x; acc0[1] += a4.y * wf.x;
                    acc0[2] += a4.z * wf.x; acc0[3] += a4.w * wf.x;
                    acc1[0] += a4.x * wf.y; acc1[1] += a4.y * wf.y;
                    acc1[2] += a4.z * wf.y; acc1[3] += a4.w * wf.y;
                }
            }
            __syncthreads();
        }

        // ================= cell update + publish h(t) =========================
        float* hdst = ringl + (size_t)slot(t) * (B * H);
        #pragma unroll
        for (int r = 0; r < 4; ++r) {
            float g0 = acc0[r] + bj0;       // gsel==0: i ; gsel==1: f
            float g1 = acc1[r] + bj1;       // gsel==0: g ; gsel==1: o
            float p0 = __shfl_xor(g0, 16, 64);
            float p1 = __shfl_xor(g1, 16, 64);
            float vi = gsel ? p0 : g0;
            float vf = gsel ? g0 : p0;
            float vg = gsel ? p1 : g1;
            float vo = gsel ? g1 : p1;
            float cn = sigf(vf) * c4[r] + sigf(vi) * tanhfast(vg);
            c4[r] = cn;
            float hv = sigf(vo) * tanhfast(cn);
            if (gsel == 0)
                __hip_atomic_store(&hdst[(size_t)(row0 + r) * H + (wg << 4) + u], hv,
                                   __ATOMIC_RELAXED, __HIP_MEMORY_SCOPE_AGENT);
        }
        __threadfence();
        __syncthreads();
        if (tid == 0)
            __hip_atomic_fetch_add(&flags[l * T + t], 1, __ATOMIC_RELEASE,
                                   __HIP_MEMORY_SCOPE_AGENT);
    }

    // ================= output projection (blocks 0..63) =======================
    if (blockIdx.x >= 64) return;
    if (tid == 0)
        while (__hip_atomic_load(&flags[(L - 1) * T + (T - 1)], __ATOMIC_ACQUIRE,
                                 __HIP_MEMORY_SCOPE_AGENT) < 64)
            __builtin_amdgcn_s_sleep(1);
    __syncthreads();

    const int b  = blockIdx.x >> 1;
    const int o0 = (blockIdx.x & 1) << 8;
    const float* h3 = ring + (size_t)(L - 1) * RING * (B * H)
                           + (size_t)slot(T - 1) * (B * H) + (size_t)b * H;
    for (int j = tid; j < H; j += 256)
        a_sh[j] = __hip_atomic_load((float*)&h3[j], __ATOMIC_RELAXED, __HIP_MEMORY_SCOPE_AGENT);
    __syncthreads();
    const int o = o0 + tid;
    float s = bout[o];
    #pragma unroll 8
    for (int j = 0; j < H; ++j)
        s += a_sh[j] * Wout[(size_t)j * D_OUT + o];
    out[(size_t)b * D_OUT + o] = s;
}

extern "C" void kernel_launch(void* const* d_in, const int* in_sizes, int n_in,
                              void* d_out, int out_size, void* d_ws, size_t ws_size,
                              hipStream_t stream) {
    const float* x    = (const float*)d_in[0];
    const float* Wx0  = (const float*)d_in[1];
    const float* Wh0  = (const float*)d_in[2];
    const float* b0   = (const float*)d_in[3];
    const float* Wx   = (const float*)d_in[4];
    const float* Wh   = (const float*)d_in[5];
    const float* bb   = (const float*)d_in[6];
    const float* Wout = (const float*)d_in[7];
    const float* bout = (const float*)d_in[8];
    float* out = (float*)d_out;

    uint32_t* Wpk  = (uint32_t*)d_ws;
    float*    ring = (float*)(Wpk + WTOT);
    int*      flags = (int*)(ring + (size_t)L * RING * B * H);

    // zero ring + flags (~4.2 MB)
    size_t zbytes = (size_t)L * RING * B * H * sizeof(float) + (size_t)L * T * sizeof(int);
    hipMemsetAsync(ring, 0, zbytes, stream);

    pack_x<<<dim3(XTOT / 256), 256, 0, stream>>>(Wx0, Wx, Wpk);
    pack_h<<<dim3(HTOT / 256), 256, 0, stream>>>(Wh0, Wh, Wpk + XTOT);

    static bool attr_set = false;
    (void)attr_set;
    hipFuncSetAttribute(reinterpret_cast<const void*>(&lstm_persistent),
                        hipFuncAttributeMaxDynamicSharedMemorySize, 149504);

    lstm_persistent<<<dim3(256), dim3(256), 149504, stream>>>(
        x, b0, bb, Wout, bout, out, Wpk, ring, flags);
}

// Round 4
// 9874.476 us; speedup vs baseline: 17.1082x; 10.9737x over previous
//
#include <hip/hip_runtime.h>
#include <cmath>

// Problem constants
#define B 32
#define T 512
#define D_IN 512
#define H 1024
#define NG 4096
#define L 4
#define D_OUT 512
#define RING 8

typedef _Float16 half8 __attribute__((ext_vector_type(8)));
typedef float    floatx4 __attribute__((ext_vector_type(4)));

// ---- workspace byte offsets ----
// Wpk: per (l,wg): [w][i 0..15][nt 0..3][lane 0..63][8 halves] = 256 KB -> 64 MB total
// Xt : [t][ktg 0..15][q][m 0..31][8 halves] fp16 tiled x     -> 16 MB
// Rt : [l][slot 0..7][jt 0..31][q][m][8 halves] fp16 h ring  -> 2 MB
// h3f: fp32 [32][1024] final-layer h at T-1
// flags: int [L][T]
#define OFF_WPK 0ull
#define OFF_XT  67108864ull
#define OFF_RT  83886080ull
#define OFF_H3F 85983232ull
#define OFF_FLG 86114304ull

__device__ __forceinline__ int slot(int t) { return (t + 1) & (RING - 1); }
__device__ __forceinline__ float sigf(float x) { return 1.f / (1.f + __expf(-x)); }
__device__ __forceinline__ float tanhfast(float x) { return 2.f / (1.f + __expf(-2.f * x)) - 1.f; }

__device__ __forceinline__ void ld16(half8& d, const char* p) {
    asm volatile("global_load_dwordx4 %0, %1, off sc0 sc1" : "=v"(d) : "v"(p));
}

__device__ __forceinline__ void waitge64(const int* f) {
    while (__hip_atomic_load(f, __ATOMIC_ACQUIRE, __HIP_MEMORY_SCOPE_SYSTEM) < 64)
        __builtin_amdgcn_s_sleep(1);
}

// ---------------------------------------------------------------------------
// pack_w: fp32 weights -> fp16 B-fragments for mfma_f32_16x16x32_f16.
// B-frag layout: lane holds B[k = ktg*32 + (lane>>4)*8 + j][n = nt*1024 + wg*16 + (lane&15)]
// ktg = i*4 + w (K interleaved across waves). l=0: k in [512,1024) is zero pad.
// ---------------------------------------------------------------------------
__global__ __launch_bounds__(256) void pack_w(
    const float* __restrict__ Wx0, const float* __restrict__ Wh0,
    const float* __restrict__ Wx,  const float* __restrict__ Wh,
    uint32_t* __restrict__ dst)
{
    unsigned g = blockIdx.x * 256u + threadIdx.x;        // < 16,777,216
    unsigned lwg = g >> 16;
    int l = lwg >> 6, wg = lwg & 63;
    unsigned s = g & 65535u;
    int w  = s >> 14, i = (s >> 10) & 15, nt = (s >> 8) & 3;
    int q  = (s >> 6) & 3, jp = (s >> 4) & 3, r = s & 15;
    int k  = (i * 4 + w) * 32 + q * 8 + jp * 2;
    int n  = nt * 1024 + wg * 16 + r;

    float a, bv;
    if (l == 0) {
        if (k < 512)       { a = Wx0[(size_t)k * NG + n]; bv = Wx0[(size_t)(k + 1) * NG + n]; }
        else if (k < 1024) { a = 0.f; bv = 0.f; }
        else               { a = Wh0[(size_t)(k - 1024) * NG + n]; bv = Wh0[(size_t)(k - 1023) * NG + n]; }
    } else {
        const float* src;
        if (k < 1024) src = Wx + (size_t)(l - 1) * H * NG;
        else          src = Wh + (size_t)(l - 1) * H * NG - (size_t)1024 * NG;
        a  = src[(size_t)k * NG + n];
        bv = src[(size_t)(k + 1) * NG + n];
    }
    union { _Float16 h[2]; uint32_t u; } cv;
    cv.h[0] = (_Float16)a; cv.h[1] = (_Float16)bv;
    // u32 index == g by construction (out order matches decomposition)
    dst[(size_t)lwg * 65536 + (((size_t)(w * 16 + i) * 4 + nt) * 64 + q * 16 + r) * 4 + jp] = cv.u;
}

// ---------------------------------------------------------------------------
// tile_x: x fp32 [B][T][D_IN] -> Xt fp16 tiled [t][ktg][q][m][8]
// ---------------------------------------------------------------------------
__global__ __launch_bounds__(256) void tile_x(const float* __restrict__ x,
                                              uint32_t* __restrict__ dst)
{
    unsigned g = blockIdx.x * 256u + threadIdx.x;        // < 4,194,304
    int jp = g & 3, m = (g >> 2) & 31, q = (g >> 7) & 3, ktg = (g >> 9) & 15, t = g >> 13;
    int k = ktg * 32 + q * 8 + jp * 2;
    const float* xp = x + (size_t)m * (T * D_IN) + (size_t)t * D_IN + k;
    union { _Float16 h[2]; uint32_t u; } cv;
    cv.h[0] = (_Float16)xp[0]; cv.h[1] = (_Float16)xp[1];
    dst[g] = cv.u;
}

// ---------------------------------------------------------------------------
// Persistent MFMA LSTM. 256 blocks (4 layers x 64 wgs) x 256 threads.
// Waves split K 4-ways (interleaved ktg = 4i+w); B-frags VGPR-resident all T.
// A-frags: coalesced dwordx4 sc0sc1 loads from fp16 tiled ring/Xt,
// software-pipelined 3 groups deep with manual vmcnt.
// ---------------------------------------------------------------------------
__global__ __launch_bounds__(256, 1) void lstm_mfma(
    const float* __restrict__ b0,
    const float* __restrict__ bb,
    const float* __restrict__ Wout,
    const float* __restrict__ bout,
    float* __restrict__ out,
    const char* __restrict__ WpkB,
    const char* __restrict__ XtB,
    char* __restrict__ RtB,
    float* __restrict__ h3f,
    int*   __restrict__ flags)
{
    __shared__ floatx4 red[2048];        // [w][mt][nt][lane][4f32] = 32 KB
    __shared__ _Float16 hsh[512];        // [m][u] 1 KB
    // + 56 KB dynamic LDS (unused) forces 1 block/CU for residency guarantee

    const int tid  = threadIdx.x;
    const int l    = blockIdx.x >> 6;
    const int wg   = blockIdx.x & 63;
    const int lane = tid & 63;
    const int w    = tid >> 6;
    const int q    = lane >> 4;
    const int r    = lane & 15;
    const int laneoff = q * 512 + r * 16;

    // ---- one-time: B-fragments into registers ----
    half8 bfr[16][4];
    {
        const half8* wb = (const half8*)WpkB + (size_t)(l * 64 + wg) * 16384 + w * 4096 + lane;
        #pragma unroll
        for (int i = 0; i < 16; ++i)
            #pragma unroll
            for (int nt = 0; nt < 4; ++nt)
                bfr[i][nt] = wb[(i * 4 + nt) * 64];
    }
    if (l == 0) {
        #pragma unroll
        for (int i = 4; i < 8; ++i)
            #pragma unroll
            for (int nt = 0; nt < 4; ++nt)
                bfr[i][nt] = (half8)(_Float16)0;
    }

    // ---- biases + persistent cell state (update threads: tid<128) ----
    float bias4[4] = {0.f, 0.f, 0.f, 0.f};
    float cst[4]   = {0.f, 0.f, 0.f, 0.f};
    const float* biasl = (l == 0) ? b0 : (bb + (size_t)(l - 1) * NG);
    if (tid < 128) {
        #pragma unroll
        for (int g = 0; g < 4; ++g) bias4[g] = biasl[g * 1024 + wg * 16 + (tid & 15)];
    }

    for (int t = 0; t < T; ++t) {
        // ---- waits ----
        if (tid == 0) {
            if (t > 0)              waitge64(&flags[l * T + (t - 1)]);
            if (l > 0)              waitge64(&flags[(l - 1) * T + t]);
            if (l < L - 1 && t >= RING) waitge64(&flags[(l + 1) * T + (t - RING)]);
        }
        __syncthreads();

        // ---- per-step A bases ----
        const char* srcXb = (l == 0) ? (XtB + (size_t)t * 32768)
                                     : (RtB + (size_t)((l - 1) * 8 + slot(t)) * 65536);
        const char* srcHb = RtB + (size_t)(l * 8 + slot(t - 1)) * 65536;
        const char* axb = srcXb + w * 2048 + laneoff;
        const char* ahb = srcHb + w * 2048 + laneoff - 65536;
        const int xadj = (l == 0) ? 32768 : 0;

        floatx4 acc[2][4];
        #pragma unroll
        for (int mt = 0; mt < 2; ++mt)
            #pragma unroll
            for (int nt = 0; nt < 4; ++nt) acc[mt][nt] = (floatx4)0.f;

        half8 ab[3][4];

        // address for (i, mt=0); mt=1 adds 256
        #define AADDR(i) ((i) < 8 ? (axb + (i) * 8192 - ((i) >= 4 ? xadj : 0)) \
                                  : (ahb + (i) * 8192))
        // prologue: groups 0,1 (i = 0..3)
        { const char* p = AADDR(0); ld16(ab[0][0], p); ld16(ab[0][1], p + 256);
          p = AADDR(1);             ld16(ab[0][2], p); ld16(ab[0][3], p + 256); }
        { const char* p = AADDR(2); ld16(ab[1][0], p); ld16(ab[1][1], p + 256);
          p = AADDR(3);             ld16(ab[1][2], p); ld16(ab[1][3], p + 256); }

        #define GRP(g, N) do { \
            if ((g) < 6) { \
                const char* p_ = AADDR(2 * (g) + 4); \
                ld16(ab[((g) + 2) % 3][0], p_); ld16(ab[((g) + 2) % 3][1], p_ + 256); \
                p_ = AADDR(2 * (g) + 5); \
                ld16(ab[((g) + 2) % 3][2], p_); ld16(ab[((g) + 2) % 3][3], p_ + 256); \
            } \
            asm volatile("s_waitcnt vmcnt(" #N ")" \
                : "+v"(ab[(g) % 3][0]), "+v"(ab[(g) % 3][1]), \
                  "+v"(ab[(g) % 3][2]), "+v"(ab[(g) % 3][3])); \
            _Pragma("unroll") \
            for (int nt = 0; nt < 4; ++nt) { \
                acc[0][nt] = __builtin_amdgcn_mfma_f32_16x16x32_f16(ab[(g) % 3][0], bfr[2 * (g)][nt],     acc[0][nt], 0, 0, 0); \
                acc[1][nt] = __builtin_amdgcn_mfma_f32_16x16x32_f16(ab[(g) % 3][1], bfr[2 * (g)][nt],     acc[1][nt], 0, 0, 0); \
                acc[0][nt] = __builtin_amdgcn_mfma_f32_16x16x32_f16(ab[(g) % 3][2], bfr[2 * (g) + 1][nt], acc[0][nt], 0, 0, 0); \
                acc[1][nt] = __builtin_amdgcn_mfma_f32_16x16x32_f16(ab[(g) % 3][3], bfr[2 * (g) + 1][nt], acc[1][nt], 0, 0, 0); \
            } \
        } while (0)

        GRP(0, 8); GRP(1, 8); GRP(2, 8); GRP(3, 8);
        GRP(4, 8); GRP(5, 8); GRP(6, 4); GRP(7, 0);
        #undef GRP
        #undef AADDR

        // ---- cross-wave reduce via LDS ----
        #pragma unroll
        for (int mt = 0; mt < 2; ++mt)
            #pragma unroll
            for (int nt = 0; nt < 4; ++nt)
                red[((w * 2 + mt) * 4 + nt) * 64 + lane] = acc[mt][nt];
        __syncthreads();

        // ---- gate sums + cell update (threads 0..127) ----
        if (tid < 128) {
            const int u = tid & 15, mq = tid >> 4, mt = mq >> 2, qq = mq & 3;
            const int lp = qq * 16 + u;
            floatx4 s0 = (floatx4)0.f, s1 = (floatx4)0.f, s2 = (floatx4)0.f, s3 = (floatx4)0.f;
            #pragma unroll
            for (int w2 = 0; w2 < 4; ++w2) {
                s0 += red[((w2 * 2 + mt) * 4 + 0) * 64 + lp];
                s1 += red[((w2 * 2 + mt) * 4 + 1) * 64 + lp];
                s2 += red[((w2 * 2 + mt) * 4 + 2) * 64 + lp];
                s3 += red[((w2 * 2 + mt) * 4 + 3) * 64 + lp];
            }
            #pragma unroll
            for (int rr = 0; rr < 4; ++rr) {
                float gi = s0[rr] + bias4[0];
                float gf = s1[rr] + bias4[1];
                float gg = s2[rr] + bias4[2];
                float go = s3[rr] + bias4[3];
                float cn = sigf(gf) * cst[rr] + sigf(gi) * tanhfast(gg);
                cst[rr] = cn;
                float hv = sigf(go) * tanhfast(cn);
                int m = mt * 16 + qq * 4 + rr;
                hsh[m * 16 + u] = (_Float16)hv;
                if (t == T - 1 && l == 3) h3f[(size_t)m * 1024 + (wg << 4) + u] = hv;
            }
        }
        __syncthreads();

        // ---- publish h(t) tiled (wave 0) + flag ----
        if (tid < 64) {
            int m = tid & 31, uq = tid >> 5;
            half8 hv = *(const half8*)&hsh[m * 16 + uq * 8];
            char* dst = RtB + (size_t)(l * 8 + slot(t)) * 65536
                        + (wg >> 1) * 2048 + ((wg & 1) * 2 + uq) * 512 + m * 16;
            *(half8*)dst = hv;
        }
        if (w == 0) {
            __threadfence_system();
            if (tid == 0)
                __hip_atomic_fetch_add(&flags[l * T + t], 1, __ATOMIC_RELEASE,
                                       __HIP_MEMORY_SCOPE_SYSTEM);
        }
    }

    // ---- output projection (layer-0 blocks) ----
    if (l != 0) return;
    if (tid == 0) waitge64(&flags[(L - 1) * T + (T - 1)]);
    __syncthreads();

    const int b  = blockIdx.x >> 1;
    const int o0 = (blockIdx.x & 1) << 8;
    float* hb = (float*)red;
    for (int j = tid; j < H; j += 256)
        hb[j] = h3f[(size_t)b * H + j];
    __syncthreads();
    const int o = o0 + tid;
    float s = bout[o];
    #pragma unroll 8
    for (int j = 0; j < H; ++j)
        s += hb[j] * Wout[(size_t)j * D_OUT + o];
    out[(size_t)b * D_OUT + o] = s;
}

extern "C" void kernel_launch(void* const* d_in, const int* in_sizes, int n_in,
                              void* d_out, int out_size, void* d_ws, size_t ws_size,
                              hipStream_t stream) {
    const float* x    = (const float*)d_in[0];
    const float* Wx0  = (const float*)d_in[1];
    const float* Wh0  = (const float*)d_in[2];
    const float* b0   = (const float*)d_in[3];
    const float* Wx   = (const float*)d_in[4];
    const float* Wh   = (const float*)d_in[5];
    const float* bb   = (const float*)d_in[6];
    const float* Wout = (const float*)d_in[7];
    const float* bout = (const float*)d_in[8];
    float* out = (float*)d_out;

    char* ws = (char*)d_ws;
    uint32_t* Wpk  = (uint32_t*)(ws + OFF_WPK);
    uint32_t* Xt   = (uint32_t*)(ws + OFF_XT);
    char*     Rt   = ws + OFF_RT;
    float*    h3f  = (float*)(ws + OFF_H3F);
    int*      flags = (int*)(ws + OFF_FLG);

    hipMemsetAsync(Rt, 0, 2097152, stream);      // zero ring (h(-1) = 0)
    hipMemsetAsync(flags, 0, 8192, stream);

    pack_w<<<dim3(65536), dim3(256), 0, stream>>>(Wx0, Wh0, Wx, Wh, Wpk);
    tile_x<<<dim3(16384), dim3(256), 0, stream>>>(x, Xt);

    hipFuncSetAttribute(reinterpret_cast<const void*>(&lstm_mfma),
                        hipFuncAttributeMaxDynamicSharedMemorySize, 57344);
    lstm_mfma<<<dim3(256), dim3(256), 57344, stream>>>(
        b0, bb, Wout, bout, out, (const char*)Wpk, (const char*)Xt, Rt, h3f, flags);
}

// Round 6
// 6563.068 us; speedup vs baseline: 25.7401x; 1.5046x over previous
//
#include <hip/hip_runtime.h>
#include <cmath>

// Problem constants
#define B 32
#define T 512
#define D_IN 512
#define H 1024
#define NG 4096
#define L 4
#define D_OUT 512
#define RING 8

typedef _Float16 half8 __attribute__((ext_vector_type(8)));
typedef float    floatx4 __attribute__((ext_vector_type(4)));

// ---- workspace byte offsets ----
// Wpk: per (l,wg): [w][i 0..15][nt 0..3][lane 0..63][8 halves] = 256 KB -> 64 MB total
// Xt : [t][ktg 0..15][q][m 0..31][8 halves] fp16 tiled x     -> 16 MB
// Rt : [l][slot 0..7][ktg 0..31][q][m][8 halves] fp16 h ring -> 2 MB
// flags: int [L][T]  (count of wgs that completed (l,t))
#define OFF_WPK 0ull
#define OFF_XT  67108864ull
#define OFF_RT  83886080ull
#define OFF_FLG 86114304ull

__device__ __forceinline__ int slot(int t) { return (t + 1) & (RING - 1); }
__device__ __forceinline__ float sigf(float x) { return 1.f / (1.f + __expf(-x)); }
__device__ __forceinline__ float tanhfast(float x) { return 2.f / (1.f + __expf(-2.f * x)) - 1.f; }

// Infinity-Cache-coherent data path (bypass L1/L2; no cache maintenance needed)
__device__ __forceinline__ void ld16(half8& d, const char* p) {
    asm volatile("global_load_dwordx4 %0, %1, off sc0 sc1" : "=v"(d) : "v"(p));
}
__device__ __forceinline__ void st16(char* p, half8 v) {
    asm volatile("global_store_dwordx4 %0, %1, off sc0 sc1" :: "v"(p), "v"(v));
}

// R3-proven agent-scope acquire poll (tid 0 only)
__device__ __forceinline__ void waitge64(const int* f) {
    while (__hip_atomic_load(f, __ATOMIC_ACQUIRE, __HIP_MEMORY_SCOPE_AGENT) < 64)
        __builtin_amdgcn_s_sleep(1);
}

// ---------------------------------------------------------------------------
// pack_w: fp32 weights -> fp16 B-fragments for mfma_f32_16x16x32_f16.
// B-frag layout: lane holds B[k = ktg*32 + (lane>>4)*8 + j][n = nt*1024 + wg*16 + (lane&15)]
// ktg = i*4 + w (K interleaved across waves). l=0: k in [512,1024) is zero pad.
// ---------------------------------------------------------------------------
__global__ __launch_bounds__(256) void pack_w(
    const float* __restrict__ Wx0, const float* __restrict__ Wh0,
    const float* __restrict__ Wx,  const float* __restrict__ Wh,
    uint32_t* __restrict__ dst)
{
    unsigned g = blockIdx.x * 256u + threadIdx.x;        // < 16,777,216
    unsigned lwg = g >> 16;
    int l = lwg >> 6, wg = lwg & 63;
    unsigned s = g & 65535u;
    int w  = s >> 14, i = (s >> 10) & 15, nt = (s >> 8) & 3;
    int q  = (s >> 6) & 3, jp = (s >> 4) & 3, r = s & 15;
    int k  = (i * 4 + w) * 32 + q * 8 + jp * 2;
    int n  = nt * 1024 + wg * 16 + r;

    float a, bv;
    if (l == 0) {
        if (k < 512)       { a = Wx0[(size_t)k * NG + n]; bv = Wx0[(size_t)(k + 1) * NG + n]; }
        else if (k < 1024) { a = 0.f; bv = 0.f; }
        else               { a = Wh0[(size_t)(k - 1024) * NG + n]; bv = Wh0[(size_t)(k - 1023) * NG + n]; }
    } else {
        const float* src;
        if (k < 1024) src = Wx + (size_t)(l - 1) * H * NG;
        else          src = Wh + (size_t)(l - 1) * H * NG - (size_t)1024 * NG;
        a  = src[(size_t)k * NG + n];
        bv = src[(size_t)(k + 1) * NG + n];
    }
    union { _Float16 h[2]; uint32_t u; } cv;
    cv.h[0] = (_Float16)a; cv.h[1] = (_Float16)bv;
    dst[(size_t)lwg * 65536 + (((size_t)(w * 16 + i) * 4 + nt) * 64 + q * 16 + r) * 4 + jp] = cv.u;
}

// ---------------------------------------------------------------------------
// tile_x: x fp32 [B][T][D_IN] -> Xt fp16 tiled [t][ktg][q][m][8]
// ---------------------------------------------------------------------------
__global__ __launch_bounds__(256) void tile_x(const float* __restrict__ x,
                                              uint32_t* __restrict__ dst)
{
    unsigned g = blockIdx.x * 256u + threadIdx.x;        // < 4,194,304
    int jp = g & 3, m = (g >> 2) & 31, q = (g >> 7) & 3, ktg = (g >> 9) & 15, t = g >> 13;
    int k = ktg * 32 + q * 8 + jp * 2;
    const float* xp = x + (size_t)m * (T * D_IN) + (size_t)t * D_IN + k;
    union { _Float16 h[2]; uint32_t u; } cv;
    cv.h[0] = (_Float16)xp[0]; cv.h[1] = (_Float16)xp[1];
    dst[g] = cv.u;
}

// ---------------------------------------------------------------------------
// Persistent MFMA LSTM. 256 blocks (4 layers x 64 wgs) x 256 threads.
// Waves split K 4-ways; B-frags VGPR/AGPR-resident all T. A-frags via sc0sc1
// dwordx4 loads (IC-coherent), 3-deep manual vmcnt pipeline.
// Sync: write-through h publish + wave-0 vmcnt(0) drain + agent-scope
// RELEASE fetch_add; consumers poll with agent-scope ACQUIRE loads.
// NO __threadfence_system (the R4 565MB/19us-per-step L2-flush killer).
// ---------------------------------------------------------------------------
__global__ __launch_bounds__(256, 1) void lstm_mfma(
    const float* __restrict__ b0,
    const float* __restrict__ bb,
    const float* __restrict__ Wout,
    const float* __restrict__ bout,
    float* __restrict__ out,
    const char* __restrict__ WpkB,
    const char* __restrict__ XtB,
    char* __restrict__ RtB,
    int*   __restrict__ flags)
{
    __shared__ floatx4 red[2048];        // [w][mt][nt][lane][4f32] = 32 KB
    __shared__ _Float16 hsh[512];        // [m][u] 1 KB
    // + 56 KB dynamic LDS (unused) forces 1 block/CU

    const int tid  = threadIdx.x;
    const int l    = blockIdx.x >> 6;
    const int wg   = blockIdx.x & 63;
    const int lane = tid & 63;
    const int w    = tid >> 6;
    const int q    = lane >> 4;
    const int r    = lane & 15;
    const int laneoff = q * 512 + r * 16;

    // ---- one-time: B-fragments into registers ----
    half8 bfr[16][4];
    {
        const half8* wb = (const half8*)WpkB + (size_t)(l * 64 + wg) * 16384 + w * 4096 + lane;
        #pragma unroll
        for (int i = 0; i < 16; ++i)
            #pragma unroll
            for (int nt = 0; nt < 4; ++nt)
                bfr[i][nt] = wb[(i * 4 + nt) * 64];
    }
    if (l == 0) {
        #pragma unroll
        for (int i = 4; i < 8; ++i)
            #pragma unroll
            for (int nt = 0; nt < 4; ++nt)
                bfr[i][nt] = (half8)(_Float16)0;
    }

    // ---- biases + persistent cell state (update threads: tid<128) ----
    float bias4[4] = {0.f, 0.f, 0.f, 0.f};
    float cst[4]   = {0.f, 0.f, 0.f, 0.f};
    const float* biasl = (l == 0) ? b0 : (bb + (size_t)(l - 1) * NG);
    if (tid < 128) {
        #pragma unroll
        for (int g = 0; g < 4; ++g) bias4[g] = biasl[g * 1024 + wg * 16 + (tid & 15)];
    }

    for (int t = 0; t < T; ++t) {
        // ---- waits (tid 0, agent-scope acquire) ----
        if (tid == 0) {
            if (t > 0)              waitge64(&flags[l * T + (t - 1)]);
            if (l > 0)              waitge64(&flags[(l - 1) * T + t]);
            if (l < L - 1 && t >= RING) waitge64(&flags[(l + 1) * T + (t - RING)]);
        }
        __syncthreads();

        // ---- per-step A bases ----
        const char* srcXb = (l == 0) ? (XtB + (size_t)t * 32768)
                                     : (RtB + (size_t)((l - 1) * 8 + slot(t)) * 65536);
        const char* srcHb = RtB + (size_t)(l * 8 + slot(t - 1)) * 65536;
        const char* axb = srcXb + w * 2048 + laneoff;
        const char* ahb = srcHb + w * 2048 + laneoff - 65536;
        const int xadj = (l == 0) ? 32768 : 0;

        floatx4 acc[2][4];
        #pragma unroll
        for (int mt = 0; mt < 2; ++mt)
            #pragma unroll
            for (int nt = 0; nt < 4; ++nt) acc[mt][nt] = (floatx4)0.f;

        half8 ab[3][4];

        #define AADDR(i) ((i) < 8 ? (axb + (i) * 8192 - ((i) >= 4 ? xadj : 0)) \
                                  : (ahb + (i) * 8192))
        { const char* p = AADDR(0); ld16(ab[0][0], p); ld16(ab[0][1], p + 256);
          p = AADDR(1);             ld16(ab[0][2], p); ld16(ab[0][3], p + 256); }
        { const char* p = AADDR(2); ld16(ab[1][0], p); ld16(ab[1][1], p + 256);
          p = AADDR(3);             ld16(ab[1][2], p); ld16(ab[1][3], p + 256); }

        #define GRP(g, N) do { \
            if ((g) < 6) { \
                const char* p_ = AADDR(2 * (g) + 4); \
                ld16(ab[((g) + 2) % 3][0], p_); ld16(ab[((g) + 2) % 3][1], p_ + 256); \
                p_ = AADDR(2 * (g) + 5); \
                ld16(ab[((g) + 2) % 3][2], p_); ld16(ab[((g) + 2) % 3][3], p_ + 256); \
            } \
            asm volatile("s_waitcnt vmcnt(" #N ")" \
                : "+v"(ab[(g) % 3][0]), "+v"(ab[(g) % 3][1]), \
                  "+v"(ab[(g) % 3][2]), "+v"(ab[(g) % 3][3])); \
            _Pragma("unroll") \
            for (int nt = 0; nt < 4; ++nt) { \
                acc[0][nt] = __builtin_amdgcn_mfma_f32_16x16x32_f16(ab[(g) % 3][0], bfr[2 * (g)][nt],     acc[0][nt], 0, 0, 0); \
                acc[1][nt] = __builtin_amdgcn_mfma_f32_16x16x32_f16(ab[(g) % 3][1], bfr[2 * (g)][nt],     acc[1][nt], 0, 0, 0); \
                acc[0][nt] = __builtin_amdgcn_mfma_f32_16x16x32_f16(ab[(g) % 3][2], bfr[2 * (g) + 1][nt], acc[0][nt], 0, 0, 0); \
                acc[1][nt] = __builtin_amdgcn_mfma_f32_16x16x32_f16(ab[(g) % 3][3], bfr[2 * (g) + 1][nt], acc[1][nt], 0, 0, 0); \
            } \
        } while (0)

        GRP(0, 8); GRP(1, 8); GRP(2, 8); GRP(3, 8);
        GRP(4, 8); GRP(5, 8); GRP(6, 4); GRP(7, 0);
        #undef GRP
        #undef AADDR

        // ---- cross-wave reduce via LDS ----
        #pragma unroll
        for (int mt = 0; mt < 2; ++mt)
            #pragma unroll
            for (int nt = 0; nt < 4; ++nt)
                red[((w * 2 + mt) * 4 + nt) * 64 + lane] = acc[mt][nt];
        __syncthreads();

        // ---- gate sums + cell update (threads 0..127) ----
        if (tid < 128) {
            const int u = tid & 15, mq = tid >> 4, mt = mq >> 2, qq = mq & 3;
            const int lp = qq * 16 + u;
            floatx4 s0 = (floatx4)0.f, s1 = (floatx4)0.f, s2 = (floatx4)0.f, s3 = (floatx4)0.f;
            #pragma unroll
            for (int w2 = 0; w2 < 4; ++w2) {
                s0 += red[((w2 * 2 + mt) * 4 + 0) * 64 + lp];
                s1 += red[((w2 * 2 + mt) * 4 + 1) * 64 + lp];
                s2 += red[((w2 * 2 + mt) * 4 + 2) * 64 + lp];
                s3 += red[((w2 * 2 + mt) * 4 + 3) * 64 + lp];
            }
            #pragma unroll
            for (int rr = 0; rr < 4; ++rr) {
                float gi = s0[rr] + bias4[0];
                float gf = s1[rr] + bias4[1];
                float gg = s2[rr] + bias4[2];
                float go = s3[rr] + bias4[3];
                float cn = sigf(gf) * cst[rr] + sigf(gi) * tanhfast(gg);
                cst[rr] = cn;
                float hv = sigf(go) * tanhfast(cn);
                int m = mt * 16 + qq * 4 + rr;
                hsh[m * 16 + u] = (_Float16)hv;
            }
        }
        __syncthreads();

        // ---- publish h(t) write-through (wave 0), drain, flag ----
        if (tid < 64) {
            int m = tid & 31, uq = tid >> 5;
            half8 hv = *(const half8*)&hsh[m * 16 + uq * 8];
            char* dst = RtB + (size_t)(l * 8 + slot(t)) * 65536
                        + (wg >> 1) * 2048 + ((wg & 1) * 2 + uq) * 512 + m * 16;
            st16(dst, hv);
        }
        if (w == 0) {
            asm volatile("s_waitcnt vmcnt(0)");   // wave-0 stores acked at IC
            if (tid == 0)
                __hip_atomic_fetch_add(&flags[l * T + t], 1, __ATOMIC_RELEASE,
                                       __HIP_MEMORY_SCOPE_AGENT);
        }
    }

    // ---- output projection (layer-0 blocks) ----
    if (l != 0) return;
    if (tid == 0) waitge64(&flags[(L - 1) * T + (T - 1)]);
    __syncthreads();

    const int b  = blockIdx.x >> 1;
    const int o0 = (blockIdx.x & 1) << 8;
    const char* rt3 = RtB + (size_t)((L - 1) * 8 + slot(T - 1)) * 65536;
    float* hb = (float*)red;
    if (tid < 128) {
        int j0 = tid * 8;
        half8 hv;
        ld16(hv, rt3 + ((j0 >> 5) * 2048 + ((j0 >> 3) & 3) * 512 + b * 16));
        asm volatile("s_waitcnt vmcnt(0)" : "+v"(hv));
        #pragma unroll
        for (int k2 = 0; k2 < 8; ++k2) hb[j0 + k2] = (float)hv[k2];
    }
    __syncthreads();
    const int o = o0 + tid;
    float s = bout[o];
    #pragma unroll 8
    for (int j = 0; j < H; ++j)
        s += hb[j] * Wout[(size_t)j * D_OUT + o];
    out[(size_t)b * D_OUT + o] = s;
}

extern "C" void kernel_launch(void* const* d_in, const int* in_sizes, int n_in,
                              void* d_out, int out_size, void* d_ws, size_t ws_size,
                              hipStream_t stream) {
    const float* x    = (const float*)d_in[0];
    const float* Wx0  = (const float*)d_in[1];
    const float* Wh0  = (const float*)d_in[2];
    const float* b0   = (const float*)d_in[3];
    const float* Wx   = (const float*)d_in[4];
    const float* Wh   = (const float*)d_in[5];
    const float* bb   = (const float*)d_in[6];
    const float* Wout = (const float*)d_in[7];
    const float* bout = (const float*)d_in[8];
    float* out = (float*)d_out;

    char* ws = (char*)d_ws;
    uint32_t* Wpk  = (uint32_t*)(ws + OFF_WPK);
    uint32_t* Xt   = (uint32_t*)(ws + OFF_XT);
    char*     Rt   = ws + OFF_RT;
    int*      flags = (int*)(ws + OFF_FLG);

    hipMemsetAsync(Rt, 0, 2097152, stream);              // h(-1) = 0
    hipMemsetAsync(flags, 0, L * T * sizeof(int), stream);

    pack_w<<<dim3(65536), dim3(256), 0, stream>>>(Wx0, Wh0, Wx, Wh, Wpk);
    tile_x<<<dim3(16384), dim3(256), 0, stream>>>(x, Xt);

    hipFuncSetAttribute(reinterpret_cast<const void*>(&lstm_mfma),
                        hipFuncAttributeMaxDynamicSharedMemorySize, 57344);
    lstm_mfma<<<dim3(256), dim3(256), 57344, stream>>>(
        b0, bb, Wout, bout, out, (const char*)Wpk, (const char*)Xt, Rt, flags);
}